// Round 1
// baseline (1237.978 us; speedup 1.0000x reference)
//
#include <hip/hip_runtime.h>
#include <hip/hip_bf16.h>
#include <math.h>

// Problem constants (fixed by setup_inputs)
constexpr int BS = 2;
constexpr int NQ = 22223;   // == nv
constexpr int DM = 256;
constexpr int NH = 8;
constexpr int NL = 4;
constexpr int NP = 4;
constexpr int MROWS = BS * NQ;      // 44446

constexpr int GK = 256;  // K dim of all GEMMs
constexpr int RT = 64;   // rows per block
constexpr int TK = 32;   // K chunk

// ---------------------------------------------------------------------------
// Generic row-blocked fp32 GEMM: out[M][TN] = A[M][256] @ W[256][TN] + bias
// (+ optional residual with ld=TN). 256 threads, 64 rows/block, 8xCPT register
// tile per thread.
// ---------------------------------------------------------------------------
template<int TN>
__global__ __launch_bounds__(256) void gemm_rows(
    const float* __restrict__ A, const float* __restrict__ W,
    const float* __restrict__ bias, const float* __restrict__ resid,
    float* __restrict__ out, int M)
{
    constexpr int CPT = TN / 32;          // cols per thread (8 or 4)
    __shared__ float At[RT][TK + 1];      // [row][k], +1 pad
    __shared__ float Wt[TK][TN];

    const int tid = threadIdx.x;
    const int tx = tid & 31;              // col group
    const int ty = tid >> 5;              // row group (0..7)
    const int row0 = blockIdx.x * RT;

    float acc[8][CPT];
#pragma unroll
    for (int i = 0; i < 8; ++i)
#pragma unroll
        for (int j = 0; j < CPT; ++j) acc[i][j] = 0.f;

#pragma unroll 1
    for (int k0 = 0; k0 < GK; k0 += TK) {
        // Stage A tile (RT x TK): consecutive threads -> consecutive k (coalesced)
#pragma unroll
        for (int t = 0; t < RT * TK / 256; ++t) {
            int idx = tid + t * 256;
            int r = idx >> 5;             // idx / TK
            int k = idx & 31;             // idx % TK
            int row = row0 + r;
            if (row >= M) row = M - 1;    // clamp (value unused on store)
            At[r][k] = A[(size_t)row * GK + (k0 + k)];
        }
        // Stage W tile (TK x TN): consecutive threads -> consecutive n (coalesced)
#pragma unroll
        for (int t = 0; t < TK * TN / 256; ++t) {
            int idx = tid + t * 256;
            int n = idx % TN;
            int kk = idx / TN;
            Wt[kk][n] = W[(size_t)(k0 + kk) * TN + n];
        }
        __syncthreads();

#pragma unroll
        for (int kk = 0; kk < TK; ++kk) {
            float a[8], w[CPT];
#pragma unroll
            for (int i = 0; i < 8; ++i) a[i] = At[ty * 8 + i][kk];  // broadcast reads
#pragma unroll
            for (int j = 0; j < CPT; ++j) w[j] = Wt[kk][tx * CPT + j];
#pragma unroll
            for (int i = 0; i < 8; ++i)
#pragma unroll
                for (int j = 0; j < CPT; ++j)
                    acc[i][j] += a[i] * w[j];
        }
        __syncthreads();
    }

#pragma unroll
    for (int i = 0; i < 8; ++i) {
        int row = row0 + ty * 8 + i;
        if (row < M) {
#pragma unroll
            for (int j = 0; j < CPT; ++j) {
                int col = tx * CPT + j;
                float v = acc[i][j] + bias[col];
                if (resid) v += resid[(size_t)row * TN + col];
                out[(size_t)row * TN + col] = v;
            }
        }
    }
}

// ---------------------------------------------------------------------------
// MSDA sampling: one query per block. 256 threads = 8 heads x 32 channels.
// Reads off row + aw-logit row, softmaxes per head, bilinear-gathers vproj,
// writes the 256-wide msda row. msda_out may alias `off` (block only touches
// its own row, staged through LDS first).
// ---------------------------------------------------------------------------
__global__ __launch_bounds__(256) void msda_sample(
    const float* __restrict__ vproj, const float* __restrict__ off,
    const float* __restrict__ awl, const float* __restrict__ refp,
    const int* __restrict__ sshapes, float* __restrict__ msda_out)
{
    const int qf = blockIdx.x;            // 0 .. BS*NQ-1
    const int b = qf / NQ;
    const int tid = threadIdx.x;
    const int h = tid >> 5;
    const int c = tid & 31;

    __shared__ float sOff[256];
    __shared__ float sL[128];
    __shared__ float sRef[8];
    __shared__ int   sHW[8];

    sOff[tid] = off[(size_t)qf * 256 + tid];
    if (tid < 128) sL[tid] = awl[(size_t)qf * 128 + tid];
    if (tid < 8)  sRef[tid] = refp[(size_t)qf * 8 + tid];
    if (tid < 8)  sHW[tid] = sshapes[tid];
    __syncthreads();

    // per-head softmax stats over 16 logits (broadcast from LDS, redundant per lane)
    float mx = -1e30f;
#pragma unroll
    for (int p = 0; p < 16; ++p) mx = fmaxf(mx, sL[h * 16 + p]);
    float ssum = 0.f;
#pragma unroll
    for (int p = 0; p < 16; ++p) ssum += __expf(sL[h * 16 + p] - mx);
    float inv = 1.f / ssum;

    float acc = 0.f;
    int start = 0;
#pragma unroll
    for (int l = 0; l < NL; ++l) {
        const int Hh = sHW[l * 2 + 0];
        const int Ww = sHW[l * 2 + 1];
        const float fW = (float)Ww, fH = (float)Hh;
        const float rx = sRef[l * 2 + 0];
        const float ry = sRef[l * 2 + 1];
        const float* vf = vproj + ((size_t)(b * NQ + start)) * 256 + h * 32 + c;

#pragma unroll
        for (int p = 0; p < NP; ++p) {
            const int ci = (h * NL + l) * NP + p;
            const float aw = __expf(sL[h * 16 + l * 4 + p] - mx) * inv;
            const float ox = sOff[ci * 2 + 0];
            const float oy = sOff[ci * 2 + 1];
            const float x = (rx + ox / fW) * fW - 0.5f;
            const float y = (ry + oy / fH) * fH - 0.5f;
            const float x0f = floorf(x), y0f = floorf(y);
            const float lx = x - x0f, ly = y - y0f;
            const int x0 = (int)x0f, y0 = (int)y0f;

#pragma unroll
            for (int dy = 0; dy < 2; ++dy) {
#pragma unroll
                for (int dx = 0; dx < 2; ++dx) {
                    const int xi = x0 + dx, yi = y0 + dy;
                    const bool valid = (xi >= 0) & (xi < Ww) & (yi >= 0) & (yi < Hh);
                    const float wt = (dx ? lx : 1.f - lx) * (dy ? ly : 1.f - ly);
                    const int xc = min(max(xi, 0), Ww - 1);
                    const int yc = min(max(yi, 0), Hh - 1);
                    const float v = vf[(size_t)(yc * Ww + xc) * 256];
                    acc += valid ? (aw * wt * v) : 0.f;
                }
            }
        }
        start += Hh * Ww;
    }
    msda_out[(size_t)qf * 256 + tid] = acc;   // tid == h*32+c
}

// ---------------------------------------------------------------------------
extern "C" void kernel_launch(void* const* d_in, const int* in_sizes, int n_in,
                              void* d_out, int out_size, void* d_ws, size_t ws_size,
                              hipStream_t stream) {
    const float* query = (const float*)d_in[0];
    const float* value = (const float*)d_in[1];
    const float* refp  = (const float*)d_in[2];
    const float* W_so  = (const float*)d_in[3];
    const float* b_so  = (const float*)d_in[4];
    const float* W_aw  = (const float*)d_in[5];
    const float* b_aw  = (const float*)d_in[6];
    const float* W_vp  = (const float*)d_in[7];
    const float* b_vp  = (const float*)d_in[8];
    const float* W_op  = (const float*)d_in[9];
    const float* b_op  = (const float*)d_in[10];
    const int*   sshp  = (const int*)d_in[11];
    float* out = (float*)d_out;

    // Workspace layout (fp32):
    //   vproj : MROWS*256  (45.5 MB)
    //   off   : MROWS*256  (45.5 MB)  -- reused as msda output
    //   awl   : MROWS*128  (22.8 MB)
    float* ws = (float*)d_ws;
    float* d_vproj = ws;
    float* d_off   = d_vproj + (size_t)MROWS * 256;
    float* d_awl   = d_off   + (size_t)MROWS * 256;

    const int gemm_grid = (MROWS + RT - 1) / RT;   // 695

    // 1) v = value @ W_vp + b_vp
    hipLaunchKernelGGL((gemm_rows<256>), dim3(gemm_grid), dim3(256), 0, stream,
                       value, W_vp, b_vp, nullptr, d_vproj, MROWS);
    // 2) off = query @ W_so + b_so
    hipLaunchKernelGGL((gemm_rows<256>), dim3(gemm_grid), dim3(256), 0, stream,
                       query, W_so, b_so, nullptr, d_off, MROWS);
    // 3) aw logits = query @ W_aw + b_aw
    hipLaunchKernelGGL((gemm_rows<128>), dim3(gemm_grid), dim3(256), 0, stream,
                       query, W_aw, b_aw, nullptr, d_awl, MROWS);
    // 4) sampling (msda written over off buffer)
    hipLaunchKernelGGL(msda_sample, dim3(MROWS), dim3(256), 0, stream,
                       d_vproj, d_off, d_awl, refp, sshp, d_off);
    // 5) out = msda @ W_op + b_op + query
    hipLaunchKernelGGL((gemm_rows<256>), dim3(gemm_grid), dim3(256), 0, stream,
                       d_off, W_op, b_op, query, out, MROWS);
}

// Round 2
// 573.180 us; speedup vs baseline: 2.1598x; 2.1598x over previous
//
#include <hip/hip_runtime.h>
#include <hip/hip_bf16.h>
#include <math.h>

// Problem constants (fixed by setup_inputs)
constexpr int BS = 2;
constexpr int NQ = 22223;   // == nv
constexpr int DM = 256;
constexpr int NH = 8;
constexpr int NL = 4;
constexpr int NP = 4;
constexpr int MROWS = BS * NQ;      // 44446

// Static pyramid level geometry (SHAPES in reference is a compile-time constant)
constexpr int LH[4] = {100, 50, 25, 13};
constexpr int LW[4] = {167, 84, 42, 21};
constexpr int LSTART[4] = {0, 16700, 20900, 21950};   // cumulative H*W

constexpr int GK = 256;  // K dim of all GEMMs
constexpr int RT = 64;   // rows per block
constexpr int TK = 32;   // K chunk

// ---------------------------------------------------------------------------
// Row-blocked fp32 GEMM: out[M][TN] = A[M][256] @ W[256][TN] + bias
// (+ optional fp32 residual). Optionally writes bf16 output.
// ---------------------------------------------------------------------------
template<int TN, bool BF16OUT>
__global__ __launch_bounds__(256) void gemm_rows(
    const float* __restrict__ A, const float* __restrict__ W,
    const float* __restrict__ bias, const float* __restrict__ resid,
    void* __restrict__ outv, int M)
{
    constexpr int CPT = TN / 32;          // cols per thread (8 or 4)
    __shared__ float At[RT][TK + 1];      // [row][k], +1 pad
    __shared__ float Wt[TK][TN];

    const int tid = threadIdx.x;
    const int tx = tid & 31;              // col group
    const int ty = tid >> 5;              // row group (0..7)
    const int row0 = blockIdx.x * RT;

    float acc[8][CPT];
#pragma unroll
    for (int i = 0; i < 8; ++i)
#pragma unroll
        for (int j = 0; j < CPT; ++j) acc[i][j] = 0.f;

#pragma unroll 1
    for (int k0 = 0; k0 < GK; k0 += TK) {
#pragma unroll
        for (int t = 0; t < RT * TK / 256; ++t) {
            int idx = tid + t * 256;
            int r = idx >> 5;             // idx / TK
            int k = idx & 31;             // idx % TK
            int row = row0 + r;
            if (row >= M) row = M - 1;    // clamp (value unused on store)
            At[r][k] = A[(size_t)row * GK + (k0 + k)];
        }
#pragma unroll
        for (int t = 0; t < TK * TN / 256; ++t) {
            int idx = tid + t * 256;
            int n = idx % TN;
            int kk = idx / TN;
            Wt[kk][n] = W[(size_t)(k0 + kk) * TN + n];
        }
        __syncthreads();

#pragma unroll
        for (int kk = 0; kk < TK; ++kk) {
            float a[8], w[CPT];
#pragma unroll
            for (int i = 0; i < 8; ++i) a[i] = At[ty * 8 + i][kk];
#pragma unroll
            for (int j = 0; j < CPT; ++j) w[j] = Wt[kk][tx * CPT + j];
#pragma unroll
            for (int i = 0; i < 8; ++i)
#pragma unroll
                for (int j = 0; j < CPT; ++j)
                    acc[i][j] += a[i] * w[j];
        }
        __syncthreads();
    }

#pragma unroll
    for (int i = 0; i < 8; ++i) {
        int row = row0 + ty * 8 + i;
        if (row < M) {
#pragma unroll
            for (int j = 0; j < CPT; ++j) {
                int col = tx * CPT + j;
                float v = acc[i][j] + bias[col];
                if (resid) v += resid[(size_t)row * TN + col];
                if constexpr (BF16OUT) {
                    ((__hip_bfloat16*)outv)[(size_t)row * TN + col] = __float2bfloat16(v);
                } else {
                    ((float*)outv)[(size_t)row * TN + col] = v;
                }
            }
        }
    }
}

// ---------------------------------------------------------------------------
// MSDA sampling v2: one query per WAVE (4 queries / 256-thread block).
// lane = h*8 + s : head h (0..7), sub-lane s (0..7) owns 4 channels (float4).
// Address math redundancy is 8 lanes (was 32); vproj is bf16 (half the bytes).
// msda_out may alias `off` (row is staged to LDS before the barrier; the row's
// write happens after, and only its owning block touches it).
// ---------------------------------------------------------------------------
__device__ inline void bf2x(unsigned u, float& f0, float& f1) {
    f0 = __uint_as_float(u << 16);
    f1 = __uint_as_float(u & 0xffff0000u);
}

__global__ __launch_bounds__(256) void msda_sample2(
    const __hip_bfloat16* __restrict__ vproj,
    const float* __restrict__ off,
    const float* __restrict__ awl,
    const float* __restrict__ refp,
    float* __restrict__ msda_out)
{
    __shared__ float4 sOff4[4][64];   // 4 queries x 256 floats
    __shared__ float4 sAwl4[4][32];   // 4 queries x 128 floats
    __shared__ float  sRef[4][8];

    const int tid = threadIdx.x;
    const int q0 = blockIdx.x * 4;

    {   // cooperative staging (rows clamped; clamped rows belong to this block)
        int qq = tid >> 6, e = tid & 63;
        int row = min(q0 + qq, MROWS - 1);
        sOff4[qq][e] = reinterpret_cast<const float4*>(off + (size_t)row * 256)[e];
        if (tid < 128) {
            int qa = tid >> 5, ea = tid & 31;
            int rowa = min(q0 + qa, MROWS - 1);
            sAwl4[qa][ea] = reinterpret_cast<const float4*>(awl + (size_t)rowa * 128)[ea];
        }
        if (tid < 32) {
            int qr = tid >> 3, er = tid & 7;
            int rowr = min(q0 + qr, MROWS - 1);
            sRef[qr][er] = refp[(size_t)rowr * 8 + er];
        }
    }
    __syncthreads();

    const int w = tid >> 6;           // wave id == query slot
    const int lane = tid & 63;
    const int q = q0 + w;
    if (q >= MROWS) return;
    const int b = (q >= NQ) ? 1 : 0;
    const int h = lane >> 3;
    const int s = lane & 7;

    // per-head softmax over 16 logits (redundant across the 8 lanes of the head)
    float aw[16];
    {
        float lg[16];
#pragma unroll
        for (int i = 0; i < 4; ++i) {
            float4 v = sAwl4[w][h * 4 + i];
            lg[i * 4 + 0] = v.x; lg[i * 4 + 1] = v.y;
            lg[i * 4 + 2] = v.z; lg[i * 4 + 3] = v.w;
        }
        float mx = lg[0];
#pragma unroll
        for (int i = 1; i < 16; ++i) mx = fmaxf(mx, lg[i]);
        float ssum = 0.f;
#pragma unroll
        for (int i = 0; i < 16; ++i) { aw[i] = __expf(lg[i] - mx); ssum += aw[i]; }
        float inv = 1.f / ssum;
#pragma unroll
        for (int i = 0; i < 16; ++i) aw[i] *= inv;
    }

    const float2* offp = reinterpret_cast<const float2*>(&sOff4[w][0]);
    float acc0 = 0.f, acc1 = 0.f, acc2 = 0.f, acc3 = 0.f;

#pragma unroll
    for (int l = 0; l < 4; ++l) {
        const int W = LW[l], H = LH[l];
        const float xb = sRef[w][l * 2 + 0] * (float)W - 0.5f;
        const float yb = sRef[w][l * 2 + 1] * (float)H - 0.5f;
        const __hip_bfloat16* vl =
            vproj + ((size_t)(b * NQ + LSTART[l])) * 256 + h * 32 + s * 4;
#pragma unroll
        for (int p = 0; p < 4; ++p) {
            const int ci = h * 16 + l * 4 + p;
            float2 o2 = offp[ci];
            float x = xb + o2.x;              // == (rx + ox/W)*W - 0.5 (fp-approx)
            float y = yb + o2.y;
            float x0f = floorf(x), y0f = floorf(y);
            float lx = x - x0f, ly = y - y0f;
            int x0 = (int)x0f, y0 = (int)y0f;
            int x1 = x0 + 1, y1 = y0 + 1;
            bool vx0 = (unsigned)x0 < (unsigned)W;
            bool vx1 = (unsigned)x1 < (unsigned)W;
            bool vy0 = (unsigned)y0 < (unsigned)H;
            bool vy1 = (unsigned)y1 < (unsigned)H;
            float a = aw[l * 4 + p];
            float wx0 = vx0 ? (1.f - lx) : 0.f;
            float wx1 = vx1 ? lx : 0.f;
            float wy0 = vy0 ? (1.f - ly) * a : 0.f;
            float wy1 = vy1 ? ly * a : 0.f;
            int xc0 = vx0 ? x0 : 0;
            int xc1 = vx1 ? x1 : 0;
            int yr0 = (vy0 ? y0 : 0) * W;
            int yr1 = (vy1 ? y1 : 0) * W;
            float w00 = wx0 * wy0, w01 = wx1 * wy0;
            float w10 = wx0 * wy1, w11 = wx1 * wy1;

            uint2 r00 = *reinterpret_cast<const uint2*>(vl + (size_t)(yr0 + xc0) * 256);
            uint2 r01 = *reinterpret_cast<const uint2*>(vl + (size_t)(yr0 + xc1) * 256);
            uint2 r10 = *reinterpret_cast<const uint2*>(vl + (size_t)(yr1 + xc0) * 256);
            uint2 r11 = *reinterpret_cast<const uint2*>(vl + (size_t)(yr1 + xc1) * 256);

            float f0, f1, f2, f3;
            bf2x(r00.x, f0, f1); bf2x(r00.y, f2, f3);
            acc0 += w00 * f0; acc1 += w00 * f1; acc2 += w00 * f2; acc3 += w00 * f3;
            bf2x(r01.x, f0, f1); bf2x(r01.y, f2, f3);
            acc0 += w01 * f0; acc1 += w01 * f1; acc2 += w01 * f2; acc3 += w01 * f3;
            bf2x(r10.x, f0, f1); bf2x(r10.y, f2, f3);
            acc0 += w10 * f0; acc1 += w10 * f1; acc2 += w10 * f2; acc3 += w10 * f3;
            bf2x(r11.x, f0, f1); bf2x(r11.y, f2, f3);
            acc0 += w11 * f0; acc1 += w11 * f1; acc2 += w11 * f2; acc3 += w11 * f3;
        }
    }

    reinterpret_cast<float4*>(msda_out + (size_t)q * 256 + h * 32 + s * 4)[0] =
        make_float4(acc0, acc1, acc2, acc3);
}

// ---------------------------------------------------------------------------
extern "C" void kernel_launch(void* const* d_in, const int* in_sizes, int n_in,
                              void* d_out, int out_size, void* d_ws, size_t ws_size,
                              hipStream_t stream) {
    const float* query = (const float*)d_in[0];
    const float* value = (const float*)d_in[1];
    const float* refp  = (const float*)d_in[2];
    const float* W_so  = (const float*)d_in[3];
    const float* b_so  = (const float*)d_in[4];
    const float* W_aw  = (const float*)d_in[5];
    const float* b_aw  = (const float*)d_in[6];
    const float* W_vp  = (const float*)d_in[7];
    const float* b_vp  = (const float*)d_in[8];
    const float* W_op  = (const float*)d_in[9];
    const float* b_op  = (const float*)d_in[10];
    float* out = (float*)d_out;

    // Workspace layout:
    //   d_off   : fp32 MROWS*256  (45.5 MB)  -- reused as msda output
    //   d_awl   : fp32 MROWS*128  (22.8 MB)
    //   d_vproj : bf16 MROWS*256  (22.8 MB)
    float* ws = (float*)d_ws;
    float* d_off = ws;
    float* d_awl = d_off + (size_t)MROWS * 256;
    __hip_bfloat16* d_vproj = (__hip_bfloat16*)(d_awl + (size_t)MROWS * 128);

    const int gemm_grid = (MROWS + RT - 1) / RT;   // 695

    // 1) vproj (bf16) = value @ W_vp + b_vp
    hipLaunchKernelGGL((gemm_rows<256, true>), dim3(gemm_grid), dim3(256), 0, stream,
                       value, W_vp, b_vp, nullptr, d_vproj, MROWS);
    // 2) off = query @ W_so + b_so
    hipLaunchKernelGGL((gemm_rows<256, false>), dim3(gemm_grid), dim3(256), 0, stream,
                       query, W_so, b_so, nullptr, d_off, MROWS);
    // 3) aw logits = query @ W_aw + b_aw
    hipLaunchKernelGGL((gemm_rows<128, false>), dim3(gemm_grid), dim3(256), 0, stream,
                       query, W_aw, b_aw, nullptr, d_awl, MROWS);
    // 4) sampling (msda written over off buffer); 1 query per wave
    hipLaunchKernelGGL(msda_sample2, dim3((MROWS + 3) / 4), dim3(256), 0, stream,
                       d_vproj, d_off, d_awl, refp, d_off);
    // 5) out = msda @ W_op + b_op + query
    hipLaunchKernelGGL((gemm_rows<256, false>), dim3(gemm_grid), dim3(256), 0, stream,
                       d_off, W_op, b_op, query, out, MROWS);
}

// Round 3
// 202.178 us; speedup vs baseline: 6.1232x; 2.8350x over previous
//
#include <hip/hip_runtime.h>
#include <hip/hip_bf16.h>
#include <math.h>

typedef __hip_bfloat16 bf16;
using f32x4  = __attribute__((ext_vector_type(4))) float;
using bf16x8 = __attribute__((ext_vector_type(8))) short;

constexpr int BS = 2, NQ = 22223, MROWS = 44446;
constexpr int LH[4] = {100, 50, 25, 13};
constexpr int LW[4] = {167, 84, 42, 21};
constexpr int LSTART[4] = {0, 16700, 20900, 21950};

constexpr int BM = 128, BN = 128, BK = 32;
constexpr int LDT = 40;  // LDS row stride in bf16 elems (80 B: 16B-aligned, 2-way banks only)

// ---------------------------------------------------------------------------
// Prep: weights -> bf16, transposed to [N][K] so B-fragments are contiguous.
// Wt_cat = [W_so | W_aw] (384 x 256), bcat = [b_so | b_aw].
// ---------------------------------------------------------------------------
__global__ __launch_bounds__(256) void prep_weights(
    const float* __restrict__ W_vp, const float* __restrict__ W_so,
    const float* __restrict__ W_aw, const float* __restrict__ W_op,
    const float* __restrict__ b_so, const float* __restrict__ b_aw,
    bf16* __restrict__ Wt_vp, bf16* __restrict__ Wt_cat,
    bf16* __restrict__ Wt_op, float* __restrict__ bcat)
{
    int i = blockIdx.x * 256 + threadIdx.x;
    if (i < 256 * 256) {
        int n = i >> 8, k = i & 255;
        Wt_vp[i] = __float2bfloat16(W_vp[k * 256 + n]);
        Wt_op[i] = __float2bfloat16(W_op[k * 256 + n]);
    }
    if (i < 384 * 256) {
        int n = i >> 8, k = i & 255;
        float v = (n < 256) ? W_so[k * 256 + n] : W_aw[k * 128 + (n - 256)];
        Wt_cat[i] = __float2bfloat16(v);
    }
    if (i < 384) bcat[i] = (i < 256) ? b_so[i] : b_aw[i - 256];
}

// ---------------------------------------------------------------------------
// bf16 MFMA GEMM: out[M][N] = A[M][K=256] @ Wt[N][256]^T + bias (+resid).
// 128x128 tile, 4 waves (each 64x64 = 4x4 frags of 16x16x32), BK=32.
// A is fp32 (converted during staging) or bf16 (lda in elements).
// ---------------------------------------------------------------------------
template<bool A_BF16, bool OUT_BF16, bool RESID>
__global__ __launch_bounds__(256) void gemm_mfma(
    const void* __restrict__ Av, int lda,
    const bf16* __restrict__ Wt,
    const float* __restrict__ bias,
    const float* __restrict__ resid,      // fp32, ld 256
    void* __restrict__ outv, int ldo, int M)
{
    __shared__ bf16 As[BM * LDT];
    __shared__ bf16 Bs[BN * LDT];

    const int tid = threadIdx.x;
    const int lane = tid & 63;
    const int wv = tid >> 6;
    const int wm = (wv >> 1) * 64, wn = (wv & 1) * 64;
    const int row0 = blockIdx.x * BM;
    const int bn0 = blockIdx.y * BN;
    const int l15 = lane & 15, l4 = lane >> 4;

    f32x4 acc[4][4];
#pragma unroll
    for (int m = 0; m < 4; ++m)
#pragma unroll
        for (int n = 0; n < 4; ++n) { acc[m][n][0]=0.f; acc[m][n][1]=0.f; acc[m][n][2]=0.f; acc[m][n][3]=0.f; }

    for (int k0 = 0; k0 < 256; k0 += BK) {
        __syncthreads();
#pragma unroll
        for (int t = 0; t < 2; ++t) {
            int idx = tid + t * 256;       // 0..511
            int r = idx >> 2, s = idx & 3; // tile row, 16B slot
            {   // A tile [128][32]
                int grow = row0 + r; if (grow >= M) grow = M - 1;
                bf16 tmp[8];
                if constexpr (A_BF16) {
                    const bf16* ap = (const bf16*)Av + (size_t)grow * lda + (k0 + s * 8);
                    *(uint4*)tmp = *(const uint4*)ap;
                } else {
                    const float* ap = (const float*)Av + (size_t)grow * lda + (k0 + s * 8);
                    f32x4 v0 = *(const f32x4*)ap;
                    f32x4 v1 = *(const f32x4*)(ap + 4);
#pragma unroll
                    for (int j = 0; j < 4; ++j) tmp[j] = __float2bfloat16(v0[j]);
#pragma unroll
                    for (int j = 0; j < 4; ++j) tmp[4 + j] = __float2bfloat16(v1[j]);
                }
                *(uint4*)&As[r * LDT + s * 8] = *(const uint4*)tmp;
            }
            {   // B tile: rows of Wt (n-major, k contiguous)
                const bf16* bp = Wt + (size_t)(bn0 + r) * 256 + (k0 + s * 8);
                *(uint4*)&Bs[r * LDT + s * 8] = *(const uint4*)bp;
            }
        }
        __syncthreads();

        bf16x8 af[4], bfr[4];
#pragma unroll
        for (int m = 0; m < 4; ++m)
            af[m] = *(const bf16x8*)&As[(wm + m * 16 + l15) * LDT + l4 * 8];
#pragma unroll
        for (int n = 0; n < 4; ++n)
            bfr[n] = *(const bf16x8*)&Bs[(wn + n * 16 + l15) * LDT + l4 * 8];
#pragma unroll
        for (int m = 0; m < 4; ++m)
#pragma unroll
            for (int n = 0; n < 4; ++n)
                acc[m][n] = __builtin_amdgcn_mfma_f32_16x16x32_bf16(af[m], bfr[n], acc[m][n], 0, 0, 0);
    }

    // Epilogue: D row=(lane>>4)*4+j, col=lane&15  [m89-verified]
#pragma unroll
    for (int m = 0; m < 4; ++m) {
        int frow = row0 + wm + m * 16 + l4 * 4;
#pragma unroll
        for (int n = 0; n < 4; ++n) {
            int fcol = bn0 + wn + n * 16 + l15;
            float bb = bias[fcol];
#pragma unroll
            for (int j = 0; j < 4; ++j) {
                int r = frow + j;
                if (r < M) {
                    float v = acc[m][n][j] + bb;
                    if constexpr (RESID) v += resid[(size_t)r * 256 + fcol];
                    if constexpr (OUT_BF16)
                        ((bf16*)outv)[(size_t)r * ldo + fcol] = __float2bfloat16(v);
                    else
                        ((float*)outv)[(size_t)r * ldo + fcol] = v;
                }
            }
        }
    }
}

// ---------------------------------------------------------------------------
// MSDA sampling: one query per wave, 4/block. offawl rows are [off(256)|awl(128)]
// fp32 stride 384. msda written bf16 aliased over offawl rows (stride 768 bf16)
// — safe: each row read-staged to LDS by its owning block before the write.
// ---------------------------------------------------------------------------
__device__ inline void bf2x(unsigned u, float& f0, float& f1) {
    f0 = __uint_as_float(u << 16);
    f1 = __uint_as_float(u & 0xffff0000u);
}

__global__ __launch_bounds__(256) void msda_sample3(
    const bf16* __restrict__ vproj,
    const float* __restrict__ offawl,
    const float* __restrict__ refp,
    bf16* __restrict__ msda_out)
{
    __shared__ float4 sOff4[4][64];
    __shared__ float4 sAwl4[4][32];
    __shared__ float  sRef[4][8];

    const int tid = threadIdx.x;
    const int q0 = blockIdx.x * 4;

    {
        int qq = tid >> 6, e = tid & 63;
        int row = min(q0 + qq, MROWS - 1);
        sOff4[qq][e] = *(const float4*)(offawl + (size_t)row * 384 + e * 4);
        if (tid < 128) {
            int qa = tid >> 5, ea = tid & 31;
            int rowa = min(q0 + qa, MROWS - 1);
            sAwl4[qa][ea] = *(const float4*)(offawl + (size_t)rowa * 384 + 256 + ea * 4);
        }
        if (tid < 32) {
            int qr = tid >> 3, er = tid & 7;
            int rowr = min(q0 + qr, MROWS - 1);
            sRef[qr][er] = refp[(size_t)rowr * 8 + er];
        }
    }
    __syncthreads();

    const int w = tid >> 6;
    const int lane = tid & 63;
    const int q = q0 + w;
    if (q >= MROWS) return;
    const int b = (q >= NQ) ? 1 : 0;
    const int h = lane >> 3;
    const int s = lane & 7;

    float aw[16];
    {
        float lg[16];
#pragma unroll
        for (int i = 0; i < 4; ++i) {
            float4 v = sAwl4[w][h * 4 + i];
            lg[i * 4 + 0] = v.x; lg[i * 4 + 1] = v.y;
            lg[i * 4 + 2] = v.z; lg[i * 4 + 3] = v.w;
        }
        float mx = lg[0];
#pragma unroll
        for (int i = 1; i < 16; ++i) mx = fmaxf(mx, lg[i]);
        float ssum = 0.f;
#pragma unroll
        for (int i = 0; i < 16; ++i) { aw[i] = __expf(lg[i] - mx); ssum += aw[i]; }
        float inv = 1.f / ssum;
#pragma unroll
        for (int i = 0; i < 16; ++i) aw[i] *= inv;
    }

    const float2* offp = reinterpret_cast<const float2*>(&sOff4[w][0]);
    float acc0 = 0.f, acc1 = 0.f, acc2 = 0.f, acc3 = 0.f;

#pragma unroll
    for (int l = 0; l < 4; ++l) {
        const int W = LW[l], H = LH[l];
        const float xb = sRef[w][l * 2 + 0] * (float)W - 0.5f;
        const float yb = sRef[w][l * 2 + 1] * (float)H - 0.5f;
        const bf16* vl = vproj + ((size_t)(b * NQ + LSTART[l])) * 256 + h * 32 + s * 4;
#pragma unroll
        for (int p = 0; p < 4; ++p) {
            const int ci = h * 16 + l * 4 + p;
            float2 o2 = offp[ci];
            float x = xb + o2.x;
            float y = yb + o2.y;
            float x0f = floorf(x), y0f = floorf(y);
            float lx = x - x0f, ly = y - y0f;
            int x0 = (int)x0f, y0 = (int)y0f;
            int x1 = x0 + 1, y1 = y0 + 1;
            bool vx0 = (unsigned)x0 < (unsigned)W;
            bool vx1 = (unsigned)x1 < (unsigned)W;
            bool vy0 = (unsigned)y0 < (unsigned)H;
            bool vy1 = (unsigned)y1 < (unsigned)H;
            float a = aw[l * 4 + p];
            float wx0 = vx0 ? (1.f - lx) : 0.f;
            float wx1 = vx1 ? lx : 0.f;
            float wy0 = vy0 ? (1.f - ly) * a : 0.f;
            float wy1 = vy1 ? ly * a : 0.f;
            int xc0 = vx0 ? x0 : 0;
            int xc1 = vx1 ? x1 : 0;
            int yr0 = (vy0 ? y0 : 0) * W;
            int yr1 = (vy1 ? y1 : 0) * W;
            float w00 = wx0 * wy0, w01 = wx1 * wy0;
            float w10 = wx0 * wy1, w11 = wx1 * wy1;

            uint2 r00 = *reinterpret_cast<const uint2*>(vl + (size_t)(yr0 + xc0) * 256);
            uint2 r01 = *reinterpret_cast<const uint2*>(vl + (size_t)(yr0 + xc1) * 256);
            uint2 r10 = *reinterpret_cast<const uint2*>(vl + (size_t)(yr1 + xc0) * 256);
            uint2 r11 = *reinterpret_cast<const uint2*>(vl + (size_t)(yr1 + xc1) * 256);

            float f0, f1, f2, f3;
            bf2x(r00.x, f0, f1); bf2x(r00.y, f2, f3);
            acc0 += w00 * f0; acc1 += w00 * f1; acc2 += w00 * f2; acc3 += w00 * f3;
            bf2x(r01.x, f0, f1); bf2x(r01.y, f2, f3);
            acc0 += w01 * f0; acc1 += w01 * f1; acc2 += w01 * f2; acc3 += w01 * f3;
            bf2x(r10.x, f0, f1); bf2x(r10.y, f2, f3);
            acc0 += w10 * f0; acc1 += w10 * f1; acc2 += w10 * f2; acc3 += w10 * f3;
            bf2x(r11.x, f0, f1); bf2x(r11.y, f2, f3);
            acc0 += w11 * f0; acc1 += w11 * f1; acc2 += w11 * f2; acc3 += w11 * f3;
        }
    }

    bf16 o[4];
    o[0] = __float2bfloat16(acc0); o[1] = __float2bfloat16(acc1);
    o[2] = __float2bfloat16(acc2); o[3] = __float2bfloat16(acc3);
    *(uint2*)(msda_out + (size_t)q * 768 + h * 32 + s * 4) = *(const uint2*)o;
}

// ---------------------------------------------------------------------------
extern "C" void kernel_launch(void* const* d_in, const int* in_sizes, int n_in,
                              void* d_out, int out_size, void* d_ws, size_t ws_size,
                              hipStream_t stream) {
    const float* query = (const float*)d_in[0];
    const float* value = (const float*)d_in[1];
    const float* refp  = (const float*)d_in[2];
    const float* W_so  = (const float*)d_in[3];
    const float* b_so  = (const float*)d_in[4];
    const float* W_aw  = (const float*)d_in[5];
    const float* b_aw  = (const float*)d_in[6];
    const float* W_vp  = (const float*)d_in[7];
    const float* b_vp  = (const float*)d_in[8];
    const float* W_op  = (const float*)d_in[9];
    const float* b_op  = (const float*)d_in[10];
    float* out = (float*)d_out;

    // Workspace layout:
    //   offawl : fp32 MROWS*384 (68.3 MB)  [off|awl]; msda bf16 aliased over rows
    //   vproj  : bf16 MROWS*256 (22.8 MB)
    //   Wt_cat : bf16 384*256,  Wt_vp/Wt_op: bf16 256*256, bcat: fp32 384
    float* ws = (float*)d_ws;
    float* d_offawl = ws;
    bf16*  d_vproj  = (bf16*)(d_offawl + (size_t)MROWS * 384);
    bf16*  d_wtcat  = d_vproj + (size_t)MROWS * 256;
    bf16*  d_wtvp   = d_wtcat + 384 * 256;
    bf16*  d_wtop   = d_wtvp + 256 * 256;
    float* d_bcat   = (float*)(d_wtop + 256 * 256);

    const int gx = (MROWS + BM - 1) / BM;   // 348

    prep_weights<<<384, 256, 0, stream>>>(W_vp, W_so, W_aw, W_op, b_so, b_aw,
                                          d_wtvp, d_wtcat, d_wtop, d_bcat);
    // offawl = query @ [W_so|W_aw] + [b_so|b_aw]   (fp32 out, ld 384)
    gemm_mfma<false, false, false><<<dim3(gx, 3), 256, 0, stream>>>(
        query, 256, d_wtcat, d_bcat, nullptr, d_offawl, 384, MROWS);
    // vproj (bf16) = value @ W_vp + b_vp
    gemm_mfma<false, true, false><<<dim3(gx, 2), 256, 0, stream>>>(
        value, 256, d_wtvp, b_vp, nullptr, d_vproj, 256, MROWS);
    // sampling: msda (bf16) aliased into offawl rows
    msda_sample3<<<(MROWS + 3) / 4, 256, 0, stream>>>(
        d_vproj, d_offawl, refp, (bf16*)d_offawl);
    // out = msda @ W_op + b_op + query   (A bf16, lda 768)
    gemm_mfma<true, false, true><<<dim3(gx, 2), 256, 0, stream>>>(
        d_offawl, 768, d_wtop, b_op, query, out, 256, MROWS);
}